// Round 7
// baseline (8007.438 us; speedup 1.0000x reference)
//
#include <hip/hip_runtime.h>
#include <stdint.h>

#define SEQ   512
#define NB    256      // batch
#define SW    2048     // stream width
#define STW   1792     // state width
#define INW   256      // input width
#define NBLK  256
#define NTHR  512      // 8 waves: waves 0-3 K-lo, waves 4-7 K-hi

typedef float f32x4 __attribute__((ext_vector_type(4)));

// workspace layout (bytes)
// [0,4096): 4 group flag arrays, 1024B apart: flags[cb] = per-block seq
// [4096]: global abort flag
#define WS_S32A  8192
#define WS_S32B  (WS_S32A + NB*SW*4)
#define WS_S8A   (WS_S32B + NB*SW*4)
#define WS_S8B   (WS_S8A + NB*SW)
#define WS_H8    (WS_S8B + NB*SW)

// S8/H8 chunk-major layout: [(bb*4+strip)*64 + chunk]*512 + l*8
// element (l, j) = row (strip*16 + (l&15)), k = chunk*32 + (l>>4)*8 + j
#define CHUNK_OFF(bb,strip,ch) (((size_t)(((bb)*4+(strip))*64 + (ch)))*512)

// ---------- agent-scope (sc1) helpers: STORES write through to the coherence
// point and push-invalidate remote L2 copies (R5/R6 evidence: unfenced
// cacheable re-reads of sc1-rewritten data validate bit-exactly). ----------
__device__ __forceinline__ unsigned ald32(const void* p){
  return __hip_atomic_load((const unsigned*)p, __ATOMIC_RELAXED, __HIP_MEMORY_SCOPE_AGENT);
}
__device__ __forceinline__ void ast64(void* p, uint64_t v){
  __hip_atomic_store((uint64_t*)p, v, __ATOMIC_RELAXED, __HIP_MEMORY_SCOPE_AGENT);
}
__device__ __forceinline__ void ast32(void* p, unsigned v){
  __hip_atomic_store((unsigned*)p, v, __ATOMIC_RELAXED, __HIP_MEMORY_SCOPE_AGENT);
}

__device__ __forceinline__ uint8_t f2fp8(float v){
  int p = __builtin_amdgcn_cvt_pk_fp8_f32(v, 0.0f, 0, false);
  return (uint8_t)(p & 0xFF);
}

__device__ __forceinline__ void store_fp8x8(uint8_t* dst, float4 a, float4 b){
  int lo = 0, hi = 0;
  lo = __builtin_amdgcn_cvt_pk_fp8_f32(a.x, a.y, lo, false);
  lo = __builtin_amdgcn_cvt_pk_fp8_f32(a.z, a.w, lo, true);
  hi = __builtin_amdgcn_cvt_pk_fp8_f32(b.x, b.y, hi, false);
  hi = __builtin_amdgcn_cvt_pk_fp8_f32(b.z, b.w, hi, true);
  int2 v; v.x = lo; v.y = hi;
  *reinterpret_cast<int2*>(dst) = v;
}

__device__ __forceinline__ uint64_t pack8(const float* f){
  int lo = 0, hi = 0;
  lo = __builtin_amdgcn_cvt_pk_fp8_f32(f[0], f[1], lo, false);
  lo = __builtin_amdgcn_cvt_pk_fp8_f32(f[2], f[3], lo, true);
  hi = __builtin_amdgcn_cvt_pk_fp8_f32(f[4], f[5], hi, false);
  hi = __builtin_amdgcn_cvt_pk_fp8_f32(f[6], f[7], hi, true);
  return (uint64_t)(uint32_t)lo | ((uint64_t)(uint32_t)hi << 32);
}

__global__ void initbar(unsigned* w){
  const int i = threadIdx.x;
  #pragma unroll
  for (int k = 0; k < 8; ++k) w[i + k*256] = 0u;   // zero first 8 KiB
}

// dataflow wait: lane polls flags[prod]; exit when ALL lanes' producers >= tgt.
__device__ __forceinline__ void waitflags(unsigned* flags, unsigned tgt, int prod,
                                          unsigned* abortf, int* s_dead)
{
  if (*s_dead) return;
  long long start = clock64();
  for (;;){
    unsigned f = ald32(&flags[prod]);
    if (__ballot(f >= tgt) == ~0ull) break;
    if (ald32(abortf) != 0u){ *s_dead = 1; break; }
    if (clock64() - start > 40000000LL){
      ast32(abortf, 1u); *s_dead = 1; break;
    }
    __builtin_amdgcn_s_sleep(1);
  }
}

__device__ __forceinline__ long mfmaq(uint64_t a, long b, f32x4& acc){
  return (long)(acc = __builtin_amdgcn_mfma_f32_16x16x32_fp8_fp8((long)a, b, acc, 0, 0, 0), 0);
}

__device__ __forceinline__ void mfma16(const uint64_t* a, const uint8_t* Bp, int cbase,
                                       f32x4& e0, f32x4& e1, f32x4& o0, f32x4& o1)
{
  #pragma unroll
  for (int i = 0; i < 16; i += 2){
    const uint8_t* bp = Bp + (size_t)(cbase + i)*1024;
    long b00 = *reinterpret_cast<const long*>(bp);
    long b01 = *reinterpret_cast<const long*>(bp + 512);
    long b10 = *reinterpret_cast<const long*>(bp + 1024);
    long b11 = *reinterpret_cast<const long*>(bp + 1536);
    e0 = __builtin_amdgcn_mfma_f32_16x16x32_fp8_fp8((long)a[i],   b00, e0, 0, 0, 0);
    e1 = __builtin_amdgcn_mfma_f32_16x16x32_fp8_fp8((long)a[i],   b01, e1, 0, 0, 0);
    o0 = __builtin_amdgcn_mfma_f32_16x16x32_fp8_fp8((long)a[i+1], b10, o0, 0, 0, 0);
    o1 = __builtin_amdgcn_mfma_f32_16x16x32_fp8_fp8((long)a[i+1], b11, o1, 0, 0, 0);
  }
}

// K-half GEMM (32 chunks) with dataflow waits: wait 16 producers, load 16
// chunks, wait next 16, load, then stream 64 MFMAs. Deterministic order.
__device__ __forceinline__ void gemm_df(const uint8_t* Abase, const uint8_t* Bp, int c0,
                                        unsigned* flags, unsigned tgt, int pA, int pB,
                                        unsigned* abortf, int* s_dead,
                                        f32x4& r0, f32x4& r1)
{
  uint64_t a0[16], a1[16];
  waitflags(flags, tgt, pA, abortf, s_dead);
  asm volatile("" ::: "memory");
  #pragma unroll
  for (int i = 0; i < 16; ++i)
    a0[i] = *reinterpret_cast<const uint64_t*>(Abase + (size_t)(c0 + i)*512);
  waitflags(flags, tgt, pB, abortf, s_dead);
  asm volatile("" ::: "memory");
  #pragma unroll
  for (int i = 0; i < 16; ++i)
    a1[i] = *reinterpret_cast<const uint64_t*>(Abase + (size_t)(c0 + 16 + i)*512);
  f32x4 e0 = {0.f,0.f,0.f,0.f};
  f32x4 e1 = e0, o0 = e0, o1 = e0;
  mfma16(a0, Bp, c0,      e0, e1, o0, o1);
  mfma16(a1, Bp, c0 + 16, e0, e1, o0, o1);
  r0 = e0 + o0;
  r1 = e1 + o1;
}

extern "C" __global__ void __launch_bounds__(NTHR, 2)
rnn_main(const float* __restrict__ x, const float* __restrict__ ist,
         const float* __restrict__ W1, const float* __restrict__ b1,
         const float* __restrict__ W2, const float* __restrict__ b2,
         float* __restrict__ out, uint8_t* ws)
{
  __shared__ uint8_t Wlds[131072];   // W1 tile @0, W2 tile @65536 (fp8, fragment order)
  __shared__ float   xferf[64*34];   // transpose buffer (bytes in ph1, f32 in ph2)
  __shared__ float   redf[4][8][64]; // K-split partial-sum exchange (8 KB)
  __shared__ int     s_dead;

  uint8_t* xfer8 = reinterpret_cast<uint8_t*>(xferf);

  float*   S32[2] = { reinterpret_cast<float*>(ws + WS_S32A),
                      reinterpret_cast<float*>(ws + WS_S32B) };
  uint8_t* S8[2]  = { ws + WS_S8A, ws + WS_S8B };
  uint8_t* H8     = ws + WS_H8;

  const int tid   = threadIdx.x;
  const int blk   = blockIdx.x;
  const int cb    = blk & 63;        // col block  -> cols cb*32..+32
  const int bb    = blk >> 6;        // batch group -> rows bb*64..+64
  const int lane  = tid & 63;
  const int wv    = tid >> 6;        // 0..7
  const int strip = wv & 3;          // 16-row strip
  const int half  = wv >> 2;         // K-half
  const int l15   = lane & 15;
  const int j0    = cb * 32;
  const int bbase = bb * 64;

  unsigned* flags  = reinterpret_cast<unsigned*>(ws + (size_t)bb*1024);
  unsigned* abortf = reinterpret_cast<unsigned*>(ws + 4096);

  if (tid == 0) s_dead = 0;

  // per-wave chunk batches and producer mappings
  const int c0   = half * 32;
  const int cA   = c0 + l15;         // batch-A chunk watched by this lane
  const int cBt  = cA + 16;          // batch-B chunk
  const int pA_n = (cA < 8) ? 56 + cA : cA - 8;   // S8 producer, t>=1
  const int pB_n = cBt - 8;                       // (cBt>=16 always)

  // ---------- prologue (tid<256): weight tiles -> LDS fp8 in fragment order
  if (tid < 256){
    const int jh  = tid >> 4;        // 0..15
    const int kc0 = (tid & 15) * 8;  // 0..120
    for (int hf = 0; hf < 2; ++hf){
      const int jc = jh + hf*16;     // 0..31 local col
      const float* r1 = W1 + (size_t)(j0 + jc)*SW;
      const float* r2 = W2 + (size_t)(j0 + jc)*SW;
      #pragma unroll
      for (int p = 0; p < 16; ++p){
        const int k = kc0 + p*128;
        const int dst = (k >> 5)*1024 + (jc >> 4)*512
                      + (((jc & 15) + (((k >> 3) & 3) << 4)) << 3);
        float4 a  = *reinterpret_cast<const float4*>(r1 + k);
        float4 bq = *reinterpret_cast<const float4*>(r1 + k + 4);
        store_fp8x8(&Wlds[dst], a, bq);
        a  = *reinterpret_cast<const float4*>(r2 + k);
        bq = *reinterpret_cast<const float4*>(r2 + k + 4);
        store_fp8x8(&Wlds[65536 + dst], a, bq);
      }
    }
  }

  const float b1v0 = b1[j0 + l15];
  const float b1v1 = b1[j0 + 16 + l15];
  const float b2v0 = b2[j0 + l15];
  const float b2v1 = b2[j0 + 16 + l15];
  const float LIN = 0.99999f;
  const float UM  = (float)(1.0 - 0.99999);

  // ---------- init s(t=0): cols [0,256)=x[0], cols [256,2048)=UM*initial_state
  if (tid < 256){
    const int r   = tid >> 2, g = tid & 3;
    const int row = bbase + r;
    const int col = j0 + g*8;
    float vv[8];
    if (col < INW){
      const float* src = x + (size_t)row*INW + col;
      *reinterpret_cast<float4*>(&vv[0]) = *reinterpret_cast<const float4*>(src);
      *reinterpret_cast<float4*>(&vv[4]) = *reinterpret_cast<const float4*>(src + 4);
    } else {
      #pragma unroll
      for (int k = 0; k < 8; ++k) vv[k] = UM * ist[col - INW + k];
    }
    float* d32 = S32[0] + (size_t)row*SW + col;
    const uint64_t* qq = reinterpret_cast<const uint64_t*>(vv);
    ast64(d32 + 0, qq[0]); ast64(d32 + 2, qq[1]);
    ast64(d32 + 4, qq[2]); ast64(d32 + 6, qq[3]);
    ast64(S8[0] + CHUNK_OFF(bb, r>>4, cb) + ((r & 15) + (g << 4))*8, pack8(vv));
  }

  unsigned seq = 1;
  __syncthreads();                      // drain init stores (vmcnt 0)
  if (tid == 0) ast32(&flags[cb], seq); // publish init (seq=1)

  const uint8_t* Bp1 = Wlds + lane*8;
  const uint8_t* Bp2 = Wlds + 65536 + lane*8;
  const size_t  lane8 = (size_t)lane*8;

  for (int t = 0; t < SEQ; ++t){
    const uint8_t* S8c = S8[t & 1];
    const float*  S32c = S32[t & 1];
    uint8_t*       S8n = S8[(t + 1) & 1];
    float*        S32n = S32[(t + 1) & 1];

    const bool dog = (cb < 56) || (t == SEQ - 1);
    const unsigned tgt1 = 2u*t + 1u;   // ph1 consumes ph2(t-1) / init
    const unsigned tgt2 = 2u*t + 2u;   // ph2 consumes ph1(t)

    // ===== phase 1: H = relu(S @ W1^T + b1), all 2048 cols
    {
      const int p1A = (t == 0) ? cA  : pA_n;
      const int p1B = (t == 0) ? cBt : pB_n;
      f32x4 r0, r1;
      gemm_df(S8c + CHUNK_OFF(bb, strip, 0) + lane8, Bp1, c0,
              flags, tgt1, p1A, p1B, abortf, &s_dead, r0, r1);
      if (half == 1){
        #pragma unroll
        for (int i = 0; i < 4; ++i){
          redf[strip][i][lane]     = r0[i];
          redf[strip][4 + i][lane] = r1[i];
        }
      }
      __syncthreads();
      if (half == 0){
        #pragma unroll
        for (int i = 0; i < 4; ++i){
          float v0 = r0[i] + redf[strip][i][lane];
          float v1 = r1[i] + redf[strip][4 + i][lane];
          const int r = strip*16 + ((lane >> 4) << 2) + i;
          xfer8[r*32 + l15]      = f2fp8(fmaxf(v0 + b1v0, 0.f));
          xfer8[r*32 + 16 + l15] = f2fp8(fmaxf(v1 + b1v1, 0.f));
        }
      }
      __syncthreads();
      if (tid < 256){
        const int r = tid >> 2, g = tid & 3;
        uint64_t v = *reinterpret_cast<const uint64_t*>(&xfer8[r*32 + g*8]);
        ast64(H8 + CHUNK_OFF(bb, r>>4, cb) + ((r & 15) + (g << 4))*8, v);
      }
    }

    __syncthreads();                       // drain H8 stores
    if (tid == 0) ast32(&flags[cb], ++seq); else ++seq;   // publish ph1 (=tgt2)

    // prefetch phase-2's LIN*s operands (S32[t&1], stable this step; all
    // ph2(t-1) flags were observed block-wide during ph1's waits)
    float sv0[4], sv1[4];
    if (dog && half == 0){
      #pragma unroll
      for (int i = 0; i < 4; ++i){
        const int r = strip*16 + ((lane >> 4) << 2) + i;
        const float* srow = S32c + (size_t)(bbase + r)*SW;
        sv0[i] = srow[j0 + l15];
        sv1[i] = srow[j0 + 16 + l15];
      }
    }

    // ===== phase 2: carry = LIN*s + UM*(H @ W2^T + b2)
    if (dog){
      f32x4 r0, r1;
      gemm_df(H8 + CHUNK_OFF(bb, strip, 0) + lane8, Bp2, c0,
              flags, tgt2, cA, cBt, abortf, &s_dead, r0, r1);
      if (half == 1){
        #pragma unroll
        for (int i = 0; i < 4; ++i){
          redf[strip][i][lane]     = r0[i];
          redf[strip][4 + i][lane] = r1[i];
        }
      }
      __syncthreads();
      if (t < SEQ - 1){
        if (half == 0){
          #pragma unroll
          for (int i = 0; i < 4; ++i){
            float v0 = r0[i] + redf[strip][i][lane];
            float v1 = r1[i] + redf[strip][4 + i][lane];
            const int r = strip*16 + ((lane >> 4) << 2) + i;
            xferf[r*34 + l15]      = LIN*sv0[i] + UM*(v0 + b2v0);
            xferf[r*34 + 16 + l15] = LIN*sv1[i] + UM*(v1 + b2v1);
          }
        }
        __syncthreads();
        if (tid < 256){
          const int r = tid >> 2, g = tid & 3;
          const float* src = &xferf[r*34 + g*8];
          uint64_t q0 = *reinterpret_cast<const uint64_t*>(src + 0);
          uint64_t q1 = *reinterpret_cast<const uint64_t*>(src + 2);
          uint64_t q2 = *reinterpret_cast<const uint64_t*>(src + 4);
          uint64_t q3 = *reinterpret_cast<const uint64_t*>(src + 6);
          float* d32 = S32n + (size_t)(bbase + r)*SW + j0 + 256 + g*8;
          ast64(d32 + 0, q0); ast64(d32 + 2, q1);
          ast64(d32 + 4, q2); ast64(d32 + 6, q3);
          ast64(S8n + CHUNK_OFF(bb, r>>4, cb + 8) + ((r & 15) + (g << 4))*8, pack8(src));
        }
      } else {
        // final step: outputs = carry[:,1792:2048], states = carry[:,0:1792]
        if (half == 0){
          #pragma unroll
          for (int i = 0; i < 4; ++i){
            float v0 = r0[i] + redf[strip][i][lane];
            float v1 = r1[i] + redf[strip][4 + i][lane];
            const int r   = strip*16 + ((lane >> 4) << 2) + i;
            const int row = bbase + r;
            const int col0 = j0 + l15;
            const int col1 = j0 + 16 + l15;
            float cr0 = LIN*sv0[i] + UM*(v0 + b2v0);
            float cr1 = LIN*sv1[i] + UM*(v1 + b2v1);
            if (col0 < STW) out[NB*INW + (size_t)row*STW + col0] = cr0;
            else            out[(size_t)row*INW + (col0 - STW)]  = cr0;
            if (col1 < STW) out[NB*INW + (size_t)row*STW + col1] = cr1;
            else            out[(size_t)row*INW + (col1 - STW)]  = cr1;
          }
        }
      }
    } else {
      // x-copy: next s cols [0,256) = x[t+1]
      if (tid < 256){
        const int r   = tid >> 2, g = tid & 3;
        const int row = bbase + r;
        const int col = (cb - 56)*32 + g*8;
        const float* src = x + ((size_t)(t + 1)*NB + row)*INW + col;
        float vv[8];
        *reinterpret_cast<float4*>(&vv[0]) = *reinterpret_cast<const float4*>(src);
        *reinterpret_cast<float4*>(&vv[4]) = *reinterpret_cast<const float4*>(src + 4);
        float* d32 = S32n + (size_t)row*SW + col;
        const uint64_t* qq = reinterpret_cast<const uint64_t*>(vv);
        ast64(d32 + 0, qq[0]); ast64(d32 + 2, qq[1]);
        ast64(d32 + 4, qq[2]); ast64(d32 + 6, qq[3]);
        ast64(S8n + CHUNK_OFF(bb, r>>4, cb - 56) + ((r & 15) + (g << 4))*8, pack8(vv));
      }
    }

    if (t < SEQ - 1){
      __syncthreads();                     // drain ph2 stores
      if (tid == 0) ast32(&flags[cb], ++seq); else ++seq;  // publish ph2
    }
  }
}

extern "C" void kernel_launch(void* const* d_in, const int* in_sizes, int n_in,
                              void* d_out, int out_size, void* d_ws, size_t ws_size,
                              hipStream_t stream)
{
  const float* x   = (const float*)d_in[0];
  const float* ist = (const float*)d_in[1];
  const float* W1  = (const float*)d_in[2];
  const float* b1  = (const float*)d_in[3];
  const float* W2  = (const float*)d_in[4];
  const float* b2  = (const float*)d_in[5];
  float* out  = (float*)d_out;
  uint8_t* ws = (uint8_t*)d_ws;

  hipLaunchKernelGGL(initbar, dim3(1), dim3(256), 0, stream, (unsigned*)ws);

  void* args[] = { (void*)&x, (void*)&ist, (void*)&W1, (void*)&b1,
                   (void*)&W2, (void*)&b2, (void*)&out, (void*)&ws };
  hipError_t e = hipLaunchCooperativeKernel((void*)rnn_main, dim3(NBLK), dim3(NTHR),
                                            args, 0, stream);
  if (e != hipSuccess){
    hipLaunchKernelGGL(rnn_main, dim3(NBLK), dim3(NTHR), 0, stream,
                       x, ist, W1, b1, W2, b2, out, ws);
  }
}